// Round 4
// baseline (12223.640 us; speedup 1.0000x reference)
//
#include <hip/hip_runtime.h>
#include <cstdint>
#include <cstddef>

#define NROWS 8
#define NTHR  256
#define HSZ   256
#define ESZ   64
#define VSZ   26
#define NCOMP 15
#define BATCH 65536
#define NBLK  (BATCH / NROWS)           // 8192 blocks
#define NTOT  ((size_t)NBLK * NTHR)     // 2,097,152 threads

typedef float v2f __attribute__((ext_vector_type(2)));

__device__ __forceinline__ v2f vfma(v2f a, v2f b, v2f c) {
#if __has_builtin(__builtin_elementwise_fma)
  return __builtin_elementwise_fma(a, b, c);
#else
  v2f r; r[0] = __builtin_fmaf(a[0], b[0], c[0]); r[1] = __builtin_fmaf(a[1], b[1], c[1]);
  return r;
#endif
}

// ---------------- threefry2x32 (exact JAX semantics) ----------------
__device__ __forceinline__ uint32_t rotl32(uint32_t v, int d) {
  return (v << d) | (v >> (32 - d));
}

__device__ __forceinline__ void tf2x32(uint32_t kA, uint32_t kB,
                                       uint32_t& x0, uint32_t& x1) {
  uint32_t kC = kA ^ kB ^ 0x1BD11BDAu;
  x0 += kA; x1 += kB;
#define TFR(r) { x0 += x1; x1 = rotl32(x1, r); x1 ^= x0; }
  TFR(13) TFR(15) TFR(26) TFR(6)
  x0 += kB; x1 += kC + 1u;
  TFR(17) TFR(29) TFR(16) TFR(24)
  x0 += kC; x1 += kA + 2u;
  TFR(13) TFR(15) TFR(26) TFR(6)
  x0 += kA; x1 += kB + 3u;
  TFR(17) TFR(29) TFR(16) TFR(24)
  x0 += kB; x1 += kC + 4u;
  TFR(13) TFR(15) TFR(26) TFR(6)
  x0 += kC; x1 += kA + 5u;
#undef TFR
}

// ---------------- XLA-matching transcendentals ----------------
__device__ __forceinline__ float xla_tanh(float x) {
  #pragma clang fp contract(off)
  float ax = fabsf(x);
  float xc = fminf(fmaxf(x, -7.90531110763549805f), 7.90531110763549805f);
  float x2 = xc * xc;
  float nu = -2.76076847742355e-16f;
  nu = x2 * nu + 2.00018790482477e-13f;
  nu = x2 * nu + -8.60467152213735e-11f;
  nu = x2 * nu + 5.12229709037114e-08f;
  nu = x2 * nu + 1.48572235717979e-05f;
  nu = x2 * nu + 6.37261928875436e-04f;
  nu = x2 * nu + 4.89352455891786e-03f;
  nu = xc * nu;
  float de = 1.19825839466702e-06f;
  de = x2 * de + 1.18534705686654e-04f;
  de = x2 * de + 2.26843463243900e-03f;
  de = x2 * de + 4.89352518554385e-03f;
  float r = nu / de;
  return (ax < 0.0004f) ? x : r;
}

__device__ __forceinline__ float xla_sigmoid(float x) {
  #pragma clang fp contract(off)
  return 0.5f + 0.5f * xla_tanh(0.5f * x);
}

__device__ __forceinline__ float xla_log(float x) {
  #pragma clang fp contract(off)
  uint32_t bits = __float_as_uint(x);
  int ei = (int)(bits >> 23) - 126;
  float m = __uint_as_float((bits & 0x007FFFFFu) | 0x3F000000u);  // [0.5,1)
  bool lt = m < 0.707106781186547524f;
  float ee = (float)ei - (lt ? 1.0f : 0.0f);
  float mm = (m - 1.0f) + (lt ? m : 0.0f);
  float x2 = mm * mm;
  float x3 = x2 * mm;
  float y  = __builtin_fmaf(7.0376836292E-2f,  mm, -1.1514610310E-1f);
  float y1 = __builtin_fmaf(-1.2420140846E-1f, mm,  1.4249322787E-1f);
  float y2 = __builtin_fmaf(2.0000714765E-1f,  mm, -2.4999993993E-1f);
  y  = __builtin_fmaf(y,  mm, 1.1676998740E-1f);
  y1 = __builtin_fmaf(y1, mm, -1.6668057665E-1f);
  y2 = __builtin_fmaf(y2, mm, 3.3333331174E-1f);
  y  = __builtin_fmaf(y, x3, y1);
  y  = __builtin_fmaf(y, x3, y2);
  y  = y * x3;
  float t1 = ee * -2.12194440e-4f;
  float t2 = 0.5f * x2;
  y  = y + t1;
  mm = mm - t2;
  float t3 = ee * 0.693359375f;
  mm = mm + y;
  mm = mm + t3;
  return mm;
}

// ------- packed FMA chain: 4 gate columns x 8 rows (as 4 row-pairs), k ascending -------
// W layout raw: W[k*1024 + gate*256 + u]. lds layout: lds[k*8 + r], row-pairs natural.
// Per lane-half this is the identical scalar IEEE FMA chain -> bit-exact.
__device__ __forceinline__ void chainp(v2f aI[4], v2f aF[4], v2f aG[4], v2f aO[4],
                                       const float* lds, const float* W, int u, int nk) {
  const float* w = W + u;
  #pragma unroll 2
  for (int k = 0; k < nk; ++k) {
    float wI = w[0], wF = w[256], wG = w[512], wO = w[768];
    w += 1024;
    v2f wIv = {wI, wI}, wFv = {wF, wF}, wGv = {wG, wG}, wOv = {wO, wO};
    v2f h0 = *(const v2f*)(lds + k * 8 + 0);
    v2f h1 = *(const v2f*)(lds + k * 8 + 2);
    v2f h2 = *(const v2f*)(lds + k * 8 + 4);
    v2f h3 = *(const v2f*)(lds + k * 8 + 6);
    aI[0] = vfma(h0, wIv, aI[0]); aI[1] = vfma(h1, wIv, aI[1]);
    aI[2] = vfma(h2, wIv, aI[2]); aI[3] = vfma(h3, wIv, aI[3]);
    aF[0] = vfma(h0, wFv, aF[0]); aF[1] = vfma(h1, wFv, aF[1]);
    aF[2] = vfma(h2, wFv, aF[2]); aF[3] = vfma(h3, wFv, aF[3]);
    aG[0] = vfma(h0, wGv, aG[0]); aG[1] = vfma(h1, wGv, aG[1]);
    aG[2] = vfma(h2, wGv, aG[2]); aG[3] = vfma(h3, wGv, aG[3]);
    aO[0] = vfma(h0, wOv, aO[0]); aO[1] = vfma(h1, wOv, aO[1]);
    aO[2] = vfma(h2, wOv, aO[2]); aO[3] = vfma(h3, wOv, aO[3]);
  }
}

template<bool WSPREF, int MINW>
__global__ __launch_bounds__(NTHR, MINW) void belief_main(
    const float* __restrict__ ctx, const float* __restrict__ embed,
    const float* __restrict__ start_e, const float* __restrict__ Wp,
    const float* __restrict__ bp, const float* __restrict__ Wi,
    const float* __restrict__ Wh, const float* __restrict__ bh,
    const float* __restrict__ Wo, const float* __restrict__ bo,
    const int* __restrict__ seedp, float* __restrict__ out,
    float4* __restrict__ ctxG) {
  __shared__ __align__(16) float hT[HSZ * NROWS];    // 8 KB, h transposed [k][r]
  __shared__ __align__(16) float ovl[HSZ * NROWS];   // 8 KB overlay region
  __shared__ float boLds[VSZ];

  // overlay views: ctxT lives only in the prologue; the rest only in the loop
  float* ctxT   = ovl;                               // [256][8]
  float* prevT  = ovl;                               // [64][8]
  float* scores = ovl + ESZ * NROWS;                 // 208 floats
  int*   tokLds = (int*)(ovl + ESZ * NROWS + NROWS * VSZ);
  uint32_t* skLds = (uint32_t*)(tokLds + NROWS);

  const int t = threadIdx.x;
  const int b0 = blockIdx.x * NROWS;
  const size_t gid = (size_t)blockIdx.x * NTHR + t;

  // ---- prologue: stage ctxT + bo ----
  #pragma unroll
  for (int r = 0; r < NROWS; ++r)
    ctxT[t * NROWS + r] = ctx[(size_t)(b0 + r) * HSZ + t];
  if (t < VSZ) boLds[t] = bo[t];
  __syncthreads();

  // ---- h0 = tanh(ctx @ Wp + bp), thread t owns hidden unit t, rows 0..7 ----
  float c[NROWS];
  {
    v2f acc[4];
    #pragma unroll
    for (int q = 0; q < 4; ++q) acc[q] = (v2f){0.f, 0.f};
    const float* wp = Wp + t;
    for (int m = 0; m < HSZ; ++m) {
      float w = wp[(size_t)m * HSZ];
      v2f wv = {w, w};
      #pragma unroll
      for (int q = 0; q < 4; ++q)
        acc[q] = vfma(*(const v2f*)(ctxT + m * NROWS + 2 * q), wv, acc[q]);
    }
    float bpv = bp[t];
    #pragma unroll
    for (int r = 0; r < NROWS; ++r) {
      float s = acc[r >> 1][r & 1] + bpv;
      hT[t * NROWS + r] = xla_tanh(s);
      c[r] = 0.0f;
    }
  }

  // ---- ctx @ Wi[0:256] prefix ----
  {
    v2f pI[4], pF[4], pG[4], pO[4];
    #pragma unroll
    for (int q = 0; q < 4; ++q) {
      pI[q] = (v2f){0.f, 0.f}; pF[q] = (v2f){0.f, 0.f};
      pG[q] = (v2f){0.f, 0.f}; pO[q] = (v2f){0.f, 0.f};
    }
    chainp(pI, pF, pG, pO, ctxT, Wi, t, HSZ);
    if constexpr (WSPREF) {
      // store to workspace (f32 round-trip is bit-exact); planes for coalescing
      #pragma unroll
      for (int q = 0; q < 4; ++q) {
        ctxG[(size_t)q * NTOT + gid]       = make_float4(pI[q][0], pI[q][1], pF[q][0], pF[q][1]);
        ctxG[(size_t)(4 + q) * NTOT + gid] = make_float4(pG[q][0], pG[q][1], pO[q][0], pO[q][1]);
      }
      __syncthreads();   // ctxT dead -> overlay switches
      for (int i = t; i < ESZ * NROWS; i += NTHR) prevT[i] = start_e[i >> 3];
      if (t < NCOMP) {
        uint32_t x0 = 0u, x1 = (uint32_t)t;
        tf2x32(0u, (uint32_t)seedp[0], x0, x1);
        skLds[2 * t] = x0; skLds[2 * t + 1] = x1;
      }
      __syncthreads();

      const float bhI = bh[t], bhF = bh[256 + t], bhG = bh[512 + t], bhO = bh[768 + t];
      const float* WiP = Wi + (size_t)HSZ * 1024;

      for (int s = 0; s < NCOMP; ++s) {
        // a = x @ Wi : reload register-prefix from ws, resume over prev rows
        v2f aI[4], aF[4], aG[4], aO[4];
        #pragma unroll
        for (int q = 0; q < 4; ++q) {
          float4 f = ctxG[(size_t)q * NTOT + gid];
          float4 g = ctxG[(size_t)(4 + q) * NTOT + gid];
          aI[q] = (v2f){f.x, f.y}; aF[q] = (v2f){f.z, f.w};
          aG[q] = (v2f){g.x, g.y}; aO[q] = (v2f){g.z, g.w};
        }
        chainp(aI, aF, aG, aO, prevT, WiP, t, ESZ);

        // b = h @ Wh (separate accumulator, added after, like XLA)
        v2f bI[4], bF[4], bG[4], bO[4];
        #pragma unroll
        for (int q = 0; q < 4; ++q) {
          bI[q] = (v2f){0.f, 0.f}; bF[q] = (v2f){0.f, 0.f};
          bG[q] = (v2f){0.f, 0.f}; bO[q] = (v2f){0.f, 0.f};
        }
        chainp(bI, bF, bG, bO, hT, Wh, t, HSZ);

        // pointwise LSTM cell (plain mul/add, XLA-style no contraction)
        float hnew[NROWS];
        {
          #pragma clang fp contract(off)
          #pragma unroll
          for (int r = 0; r < NROWS; ++r) {
            int q = r >> 1, hh = r & 1;
            float gi = (aI[q][hh] + bI[q][hh]) + bhI;
            float gf = (aF[q][hh] + bF[q][hh]) + bhF;
            float gg = (aG[q][hh] + bG[q][hh]) + bhG;
            float go = (aO[q][hh] + bO[q][hh]) + bhO;
            float si = xla_sigmoid(gi);
            float sf = xla_sigmoid(gf);
            float tg = xla_tanh(gg);
            float so = xla_sigmoid(go);
            float cn = sf * c[r] + si * tg;
            c[r] = cn;
            hnew[r] = so * xla_tanh(cn);
          }
        }
        __syncthreads();
        #pragma unroll
        for (int r = 0; r < NROWS; ++r) hT[t * NROWS + r] = hnew[r];
        __syncthreads();

        // logits + gumbel + scores (208 active threads)
        uint32_t sk0 = skLds[2 * s], sk1 = skLds[2 * s + 1];
        if (t < NROWS * VSZ) {
          int r = t / VSZ, v = t - r * VSZ;
          float acc = 0.0f;
          for (int k = 0; k < HSZ; ++k)
            acc = __builtin_fmaf(hT[k * NROWS + r], Wo[k * VSZ + v], acc);
          float logit = acc + boLds[v];
          out[(size_t)(b0 + r) * (NCOMP * VSZ) + s * VSZ + v] = logit;

          uint32_t n = (uint32_t)(b0 + r) * VSZ + (uint32_t)v;
          uint32_t x0 = 0u, x1 = n;
          tf2x32(sk0, sk1, x0, x1);
          uint32_t rb = x0 ^ x1;
          float f = __uint_as_float((rb >> 9) | 0x3F800000u) - 1.0f;
          float uu;
          {
            #pragma clang fp contract(off)
            uu = f + 1.17549435082228751e-38f;
          }
          uu = fmaxf(1.17549435082228751e-38f, uu);
          float l1 = xla_log(uu);
          float g = -xla_log(-l1);
          {
            #pragma clang fp contract(off)
            scores[r * VSZ + v] = g + logit;
          }
        }
        __syncthreads();

        if (t < NROWS) {
          float mbest = scores[t * VSZ];
          int ibest = 0;
          for (int v = 1; v < VSZ; ++v) {
            float sc = scores[t * VSZ + v];
            if (sc > mbest) { mbest = sc; ibest = v; }
          }
          tokLds[t] = ibest;
          out[(size_t)BATCH * (NCOMP * VSZ) + (size_t)(b0 + t) * NCOMP + s] = (float)ibest;
        }
        __syncthreads();
        if (s < NCOMP - 1) {
          for (int i = t; i < ESZ * NROWS; i += NTHR) {
            int e = i >> 3, r = i & 7;
            prevT[i] = embed[tokLds[r] * ESZ + e];
          }
        }
        __syncthreads();
      }
    } else {
      // ---- fallback: keep prefix in registers (higher pressure, MINW=3) ----
      __syncthreads();
      for (int i = t; i < ESZ * NROWS; i += NTHR) prevT[i] = start_e[i >> 3];
      if (t < NCOMP) {
        uint32_t x0 = 0u, x1 = (uint32_t)t;
        tf2x32(0u, (uint32_t)seedp[0], x0, x1);
        skLds[2 * t] = x0; skLds[2 * t + 1] = x1;
      }
      __syncthreads();

      const float bhI = bh[t], bhF = bh[256 + t], bhG = bh[512 + t], bhO = bh[768 + t];
      const float* WiP = Wi + (size_t)HSZ * 1024;

      for (int s = 0; s < NCOMP; ++s) {
        v2f aI[4], aF[4], aG[4], aO[4];
        #pragma unroll
        for (int q = 0; q < 4; ++q) { aI[q] = pI[q]; aF[q] = pF[q]; aG[q] = pG[q]; aO[q] = pO[q]; }
        chainp(aI, aF, aG, aO, prevT, WiP, t, ESZ);
        v2f bI[4], bF[4], bG[4], bO[4];
        #pragma unroll
        for (int q = 0; q < 4; ++q) {
          bI[q] = (v2f){0.f, 0.f}; bF[q] = (v2f){0.f, 0.f};
          bG[q] = (v2f){0.f, 0.f}; bO[q] = (v2f){0.f, 0.f};
        }
        chainp(bI, bF, bG, bO, hT, Wh, t, HSZ);

        float hnew[NROWS];
        {
          #pragma clang fp contract(off)
          #pragma unroll
          for (int r = 0; r < NROWS; ++r) {
            int q = r >> 1, hh = r & 1;
            float gi = (aI[q][hh] + bI[q][hh]) + bhI;
            float gf = (aF[q][hh] + bF[q][hh]) + bhF;
            float gg = (aG[q][hh] + bG[q][hh]) + bhG;
            float go = (aO[q][hh] + bO[q][hh]) + bhO;
            float si = xla_sigmoid(gi);
            float sf = xla_sigmoid(gf);
            float tg = xla_tanh(gg);
            float so = xla_sigmoid(go);
            float cn = sf * c[r] + si * tg;
            c[r] = cn;
            hnew[r] = so * xla_tanh(cn);
          }
        }
        __syncthreads();
        #pragma unroll
        for (int r = 0; r < NROWS; ++r) hT[t * NROWS + r] = hnew[r];
        __syncthreads();

        uint32_t sk0 = skLds[2 * s], sk1 = skLds[2 * s + 1];
        if (t < NROWS * VSZ) {
          int r = t / VSZ, v = t - r * VSZ;
          float acc = 0.0f;
          for (int k = 0; k < HSZ; ++k)
            acc = __builtin_fmaf(hT[k * NROWS + r], Wo[k * VSZ + v], acc);
          float logit = acc + boLds[v];
          out[(size_t)(b0 + r) * (NCOMP * VSZ) + s * VSZ + v] = logit;
          uint32_t n = (uint32_t)(b0 + r) * VSZ + (uint32_t)v;
          uint32_t x0 = 0u, x1 = n;
          tf2x32(sk0, sk1, x0, x1);
          uint32_t rb = x0 ^ x1;
          float f = __uint_as_float((rb >> 9) | 0x3F800000u) - 1.0f;
          float uu;
          {
            #pragma clang fp contract(off)
            uu = f + 1.17549435082228751e-38f;
          }
          uu = fmaxf(1.17549435082228751e-38f, uu);
          float l1 = xla_log(uu);
          float g = -xla_log(-l1);
          {
            #pragma clang fp contract(off)
            scores[r * VSZ + v] = g + logit;
          }
        }
        __syncthreads();
        if (t < NROWS) {
          float mbest = scores[t * VSZ];
          int ibest = 0;
          for (int v = 1; v < VSZ; ++v) {
            float sc = scores[t * VSZ + v];
            if (sc > mbest) { mbest = sc; ibest = v; }
          }
          tokLds[t] = ibest;
          out[(size_t)BATCH * (NCOMP * VSZ) + (size_t)(b0 + t) * NCOMP + s] = (float)ibest;
        }
        __syncthreads();
        if (s < NCOMP - 1) {
          for (int i = t; i < ESZ * NROWS; i += NTHR) {
            int e = i >> 3, r = i & 7;
            prevT[i] = embed[tokLds[r] * ESZ + e];
          }
        }
        __syncthreads();
      }
    }
  }
}

extern "C" void kernel_launch(void* const* d_in, const int* in_sizes, int n_in,
                              void* d_out, int out_size, void* d_ws, size_t ws_size,
                              hipStream_t stream) {
  const float* ctx     = (const float*)d_in[0];
  const float* embed   = (const float*)d_in[1];
  const float* start_e = (const float*)d_in[2];
  const float* Wp      = (const float*)d_in[3];
  const float* bp      = (const float*)d_in[4];
  const float* Wi      = (const float*)d_in[5];
  const float* Wh      = (const float*)d_in[6];
  const float* bh      = (const float*)d_in[7];
  const float* Wo      = (const float*)d_in[8];
  const float* bo      = (const float*)d_in[9];
  const int*   seedp   = (const int*)d_in[10];
  float* out = (float*)d_out;

  size_t need = NTOT * 8 * sizeof(float4);   // 256 MiB gates prefix
  float4* ctxG = (float4*)d_ws;

  if (d_ws != nullptr && ws_size >= need) {
    hipLaunchKernelGGL((belief_main<true, 4>), dim3(NBLK), dim3(NTHR), 0, stream,
                       ctx, embed, start_e, Wp, bp, Wi, Wh, bh, Wo, bo, seedp, out, ctxG);
  } else {
    hipLaunchKernelGGL((belief_main<false, 3>), dim3(NBLK), dim3(NTHR), 0, stream,
                       ctx, embed, start_e, Wp, bp, Wi, Wh, bh, Wo, bo, seedp, out, ctxG);
  }
}

// Round 5
// 11272.854 us; speedup vs baseline: 1.0843x; 1.0843x over previous
//
#include <hip/hip_runtime.h>
#include <cstdint>
#include <cstddef>

#define NROWS 8
#define NTHR  256
#define HSZ   256
#define ESZ   64
#define VSZ   26
#define NCOMP 15
#define BATCH 65536
#define NBLK  (BATCH / NROWS)           // 8192 blocks

// ---------------- threefry2x32 (exact JAX semantics) ----------------
__device__ __forceinline__ uint32_t rotl32(uint32_t v, int d) {
  return (v << d) | (v >> (32 - d));
}

__device__ __forceinline__ void tf2x32(uint32_t kA, uint32_t kB,
                                       uint32_t& x0, uint32_t& x1) {
  uint32_t kC = kA ^ kB ^ 0x1BD11BDAu;
  x0 += kA; x1 += kB;
#define TFR(r) { x0 += x1; x1 = rotl32(x1, r); x1 ^= x0; }
  TFR(13) TFR(15) TFR(26) TFR(6)
  x0 += kB; x1 += kC + 1u;
  TFR(17) TFR(29) TFR(16) TFR(24)
  x0 += kC; x1 += kA + 2u;
  TFR(13) TFR(15) TFR(26) TFR(6)
  x0 += kA; x1 += kB + 3u;
  TFR(17) TFR(29) TFR(16) TFR(24)
  x0 += kB; x1 += kC + 4u;
  TFR(13) TFR(15) TFR(26) TFR(6)
  x0 += kC; x1 += kA + 5u;
#undef TFR
}

// ---------------- XLA-matching transcendentals ----------------
__device__ __forceinline__ float xla_tanh(float x) {
  #pragma clang fp contract(off)
  float ax = fabsf(x);
  float xc = fminf(fmaxf(x, -7.90531110763549805f), 7.90531110763549805f);
  float x2 = xc * xc;
  float nu = -2.76076847742355e-16f;
  nu = x2 * nu + 2.00018790482477e-13f;
  nu = x2 * nu + -8.60467152213735e-11f;
  nu = x2 * nu + 5.12229709037114e-08f;
  nu = x2 * nu + 1.48572235717979e-05f;
  nu = x2 * nu + 6.37261928875436e-04f;
  nu = x2 * nu + 4.89352455891786e-03f;
  nu = xc * nu;
  float de = 1.19825839466702e-06f;
  de = x2 * de + 1.18534705686654e-04f;
  de = x2 * de + 2.26843463243900e-03f;
  de = x2 * de + 4.89352518554385e-03f;
  float r = nu / de;
  return (ax < 0.0004f) ? x : r;
}

__device__ __forceinline__ float xla_sigmoid(float x) {
  #pragma clang fp contract(off)
  return 0.5f + 0.5f * xla_tanh(0.5f * x);
}

__device__ __forceinline__ float xla_log(float x) {
  #pragma clang fp contract(off)
  uint32_t bits = __float_as_uint(x);
  int ei = (int)(bits >> 23) - 126;
  float m = __uint_as_float((bits & 0x007FFFFFu) | 0x3F000000u);  // [0.5,1)
  bool lt = m < 0.707106781186547524f;
  float ee = (float)ei - (lt ? 1.0f : 0.0f);
  float mm = (m - 1.0f) + (lt ? m : 0.0f);
  float x2 = mm * mm;
  float x3 = x2 * mm;
  float y  = __builtin_fmaf(7.0376836292E-2f,  mm, -1.1514610310E-1f);
  float y1 = __builtin_fmaf(-1.2420140846E-1f, mm,  1.4249322787E-1f);
  float y2 = __builtin_fmaf(2.0000714765E-1f,  mm, -2.4999993993E-1f);
  y  = __builtin_fmaf(y,  mm, 1.1676998740E-1f);
  y1 = __builtin_fmaf(y1, mm, -1.6668057665E-1f);
  y2 = __builtin_fmaf(y2, mm, 3.3333331174E-1f);
  y  = __builtin_fmaf(y, x3, y1);
  y  = __builtin_fmaf(y, x3, y2);
  y  = y * x3;
  float t1 = ee * -2.12194440e-4f;
  float t2 = 0.5f * x2;
  y  = y + t1;
  mm = mm - t2;
  float t3 = ee * 0.693359375f;
  mm = mm + y;
  mm = mm + t3;
  return mm;
}

// ---- scalar FMA chain: 4 gate cols x 8 rows, k ascending (bit-exact order) ----
// W layout: W[k*1024 + gate*256 + u]; lds layout: lds[k*8 + r] (broadcast reads).
__device__ __forceinline__ void chain8(float* aI, float* aF, float* aG, float* aO,
                                       const float* lds, const float* W, int u, int nk) {
  const float* w = W + u;
  #pragma unroll 2
  for (int k = 0; k < nk; ++k) {
    float wI = w[0], wF = w[256], wG = w[512], wO = w[768];
    w += 1024;
    float hv[8];
    *(float4*)&hv[0] = *(const float4*)(lds + k * 8);
    *(float4*)&hv[4] = *(const float4*)(lds + k * 8 + 4);
    #pragma unroll
    for (int j = 0; j < 8; ++j) {
      aI[j] = __builtin_fmaf(hv[j], wI, aI[j]);
      aF[j] = __builtin_fmaf(hv[j], wF, aF[j]);
      aG[j] = __builtin_fmaf(hv[j], wG, aG[j]);
      aO[j] = __builtin_fmaf(hv[j], wO, aO[j]);
    }
  }
}

__global__ __launch_bounds__(NTHR, 2) void belief_main(
    const float* __restrict__ ctx, const float* __restrict__ embed,
    const float* __restrict__ start_e, const float* __restrict__ Wp,
    const float* __restrict__ bp, const float* __restrict__ Wi,
    const float* __restrict__ Wh, const float* __restrict__ bh,
    const float* __restrict__ Wo, const float* __restrict__ bo,
    const int* __restrict__ seedp, float* __restrict__ out) {
  // G0[r][g]: ctx@Wi prefix, g = gate*256 + u. First 8KB doubles as ctxT in prologue.
  __shared__ __align__(16) float G0[NROWS * 1024];    // 32 KB
  __shared__ __align__(16) float hT[HSZ * NROWS];     // 8 KB, h transposed [k][r]
  __shared__ __align__(16) float prevT[ESZ * NROWS];  // 2 KB, prev embed [e][r]
  __shared__ float scores[NROWS * VSZ];
  __shared__ float boLds[VSZ];
  __shared__ int tokLds[NROWS];
  __shared__ uint32_t skLds[NCOMP * 2];

  float* ctxT = G0;                                   // prologue-only alias

  const int t = threadIdx.x;
  const int b0 = blockIdx.x * NROWS;

  // ---- prologue: stage ctxT + bo ----
  #pragma unroll
  for (int r = 0; r < NROWS; ++r)
    ctxT[t * NROWS + r] = ctx[(size_t)(b0 + r) * HSZ + t];
  if (t < VSZ) boLds[t] = bo[t];
  __syncthreads();

  // ---- h0 = tanh(ctx @ Wp + bp), thread t owns hidden unit t, rows 0..7 ----
  float c[NROWS];
  {
    float acc[NROWS];
    #pragma unroll
    for (int r = 0; r < NROWS; ++r) acc[r] = 0.0f;
    const float* wp = Wp + t;
    #pragma unroll 2
    for (int m = 0; m < HSZ; ++m) {
      float w = wp[(size_t)m * HSZ];
      float hv[8];
      *(float4*)&hv[0] = *(const float4*)&ctxT[m * NROWS];
      *(float4*)&hv[4] = *(const float4*)&ctxT[m * NROWS + 4];
      #pragma unroll
      for (int j = 0; j < 8; ++j) acc[j] = __builtin_fmaf(hv[j], w, acc[j]);
    }
    float bpv = bp[t];
    #pragma unroll
    for (int r = 0; r < NROWS; ++r) {
      float s = acc[r] + bpv;
      hT[t * NROWS + r] = xla_tanh(s);
      c[r] = 0.0f;
    }
  }

  // ---- ctx @ Wi[0:256] prefix into registers, then park in LDS G0 ----
  {
    float pI[NROWS], pF[NROWS], pG[NROWS], pO[NROWS];
    #pragma unroll
    for (int r = 0; r < NROWS; ++r) { pI[r] = 0.f; pF[r] = 0.f; pG[r] = 0.f; pO[r] = 0.f; }
    chain8(pI, pF, pG, pO, ctxT, Wi, t, HSZ);
    __syncthreads();                 // everyone done reading ctxT -> reuse as G0
    #pragma unroll
    for (int r = 0; r < NROWS; ++r) {
      G0[r * 1024 + t]       = pI[r];
      G0[r * 1024 + 256 + t] = pF[r];
      G0[r * 1024 + 512 + t] = pG[r];
      G0[r * 1024 + 768 + t] = pO[r];
    }
  }
  // stage prev embed + subkeys (distinct regions; barrier below covers all)
  for (int i = t; i < ESZ * NROWS; i += NTHR) prevT[i] = start_e[i >> 3];
  if (t < NCOMP) {
    uint32_t x0 = 0u, x1 = (uint32_t)t;   // partitionable split: tf(key, 0, t)
    tf2x32(0u, (uint32_t)seedp[0], x0, x1);
    skLds[2 * t] = x0; skLds[2 * t + 1] = x1;
  }
  __syncthreads();

  const float bhI = bh[t], bhF = bh[256 + t], bhG = bh[512 + t], bhO = bh[768 + t];
  const float* WiP = Wi + (size_t)HSZ * 1024;    // prev-embed rows of Wi

  for (int s = 0; s < NCOMP; ++s) {
    // b = h @ Wh (separate accumulator, added after, like XLA)
    float bI[NROWS], bF[NROWS], bG[NROWS], bO[NROWS];
    #pragma unroll
    for (int r = 0; r < NROWS; ++r) { bI[r] = 0.f; bF[r] = 0.f; bG[r] = 0.f; bO[r] = 0.f; }
    chain8(bI, bF, bG, bO, hT, Wh, t, HSZ);

    // a = x @ Wi: resume ctx-prefix from LDS G0, continue over prev rows
    float aI[NROWS], aF[NROWS], aG[NROWS], aO[NROWS];
    #pragma unroll
    for (int r = 0; r < NROWS; ++r) {
      aI[r] = G0[r * 1024 + t];
      aF[r] = G0[r * 1024 + 256 + t];
      aG[r] = G0[r * 1024 + 512 + t];
      aO[r] = G0[r * 1024 + 768 + t];
    }
    chain8(aI, aF, aG, aO, prevT, WiP, t, ESZ);

    // pointwise LSTM cell (plain mul/add, XLA-style no contraction)
    float hnew[NROWS];
    {
      #pragma clang fp contract(off)
      #pragma unroll
      for (int r = 0; r < NROWS; ++r) {
        float gi = (aI[r] + bI[r]) + bhI;
        float gf = (aF[r] + bF[r]) + bhF;
        float gg = (aG[r] + bG[r]) + bhG;
        float go = (aO[r] + bO[r]) + bhO;
        float si = xla_sigmoid(gi);
        float sf = xla_sigmoid(gf);
        float tg = xla_tanh(gg);
        float so = xla_sigmoid(go);
        float cn = sf * c[r] + si * tg;
        c[r] = cn;
        hnew[r] = so * xla_tanh(cn);
      }
    }
    __syncthreads();                       // all waves done reading hT/prevT
    #pragma unroll
    for (int r = 0; r < NROWS; ++r) hT[t * NROWS + r] = hnew[r];
    __syncthreads();

    // logits + gumbel + scores (208 active threads)
    uint32_t sk0 = skLds[2 * s], sk1 = skLds[2 * s + 1];
    if (t < NROWS * VSZ) {
      int r = t / VSZ, v = t - r * VSZ;
      float acc = 0.0f;
      #pragma unroll 4
      for (int k = 0; k < HSZ; ++k)
        acc = __builtin_fmaf(hT[k * NROWS + r], Wo[k * VSZ + v], acc);
      float logit = acc + boLds[v];
      out[(size_t)(b0 + r) * (NCOMP * VSZ) + s * VSZ + v] = logit;

      uint32_t n = (uint32_t)(b0 + r) * VSZ + (uint32_t)v;
      uint32_t x0 = 0u, x1 = n;
      tf2x32(sk0, sk1, x0, x1);
      uint32_t rb = x0 ^ x1;
      float f = __uint_as_float((rb >> 9) | 0x3F800000u) - 1.0f;
      float uu;
      {
        #pragma clang fp contract(off)
        uu = f + 1.17549435082228751e-38f;
      }
      uu = fmaxf(1.17549435082228751e-38f, uu);
      float l1 = xla_log(uu);
      float g = -xla_log(-l1);
      {
        #pragma clang fp contract(off)
        scores[r * VSZ + v] = g + logit;
      }
    }
    __syncthreads();

    // argmax (first max index), write sample, pick next embedding
    if (t < NROWS) {
      float mbest = scores[t * VSZ];
      int ibest = 0;
      for (int v = 1; v < VSZ; ++v) {
        float sc = scores[t * VSZ + v];
        if (sc > mbest) { mbest = sc; ibest = v; }
      }
      tokLds[t] = ibest;
      out[(size_t)BATCH * (NCOMP * VSZ) + (size_t)(b0 + t) * NCOMP + s] = (float)ibest;
    }
    __syncthreads();
    if (s < NCOMP - 1) {
      for (int i = t; i < ESZ * NROWS; i += NTHR) {
        int e = i >> 3, r = i & 7;
        prevT[i] = embed[tokLds[r] * ESZ + e];
      }
    }
    __syncthreads();
  }
}

extern "C" void kernel_launch(void* const* d_in, const int* in_sizes, int n_in,
                              void* d_out, int out_size, void* d_ws, size_t ws_size,
                              hipStream_t stream) {
  const float* ctx     = (const float*)d_in[0];
  const float* embed   = (const float*)d_in[1];
  const float* start_e = (const float*)d_in[2];
  const float* Wp      = (const float*)d_in[3];
  const float* bp      = (const float*)d_in[4];
  const float* Wi      = (const float*)d_in[5];
  const float* Wh      = (const float*)d_in[6];
  const float* bh      = (const float*)d_in[7];
  const float* Wo      = (const float*)d_in[8];
  const float* bo      = (const float*)d_in[9];
  const int*   seedp   = (const int*)d_in[10];
  float* out = (float*)d_out;

  hipLaunchKernelGGL(belief_main, dim3(NBLK), dim3(NTHR), 0, stream,
                     ctx, embed, start_e, Wp, bp, Wi, Wh, bh, Wo, bo, seedp, out);
}